// Round 5
// baseline (49.053 us; speedup 1.0000x reference)
//
#include <hip/hip_runtime.h>

// out[n, d] = x[n, d] * weight[d] + bias[d]
// x: (8192, 4096) fp32, weight/bias: (4096,) fp32, out: (8192, 4096) fp32.
// Memory-bound: 128 MiB read + 128 MiB write -> roofline ~42.6 us @ 6.29 TB/s
// measured copy ceiling (same 1:1 r:w mix).
// R1: 45.95 us cached path (93% of ceiling)  <- best so far
// R2/R3: nontemporal ld/st -> 50.96 us (REGRESSED: nt hurts on MI355X; reverted)
// R4: #pragma unroll 4 -> 46.96 us (neutral; compiler kept ld->st serialized)
// R5: explicit 4-wide load batch (named regs, loads issue back-to-back) to
//     raise per-wave outstanding VMEM. If neutral -> R1 is the roofline.

typedef float f32x4 __attribute__((ext_vector_type(4)));

constexpr int kD = 4096;
constexpr int kTokens = 8192;
constexpr long long kN = (long long)kTokens * kD;      // 33554432 elements
constexpr int kNVec = (int)(kN / 4);                   // 8388608 float4s
constexpr int kDVec = kD / 4;                          // 1024 float4s per row
constexpr int kGrid = 2048;
constexpr int kBlock = 256;
constexpr int kStride = kGrid * kBlock;                // 524288, multiple of kDVec
constexpr int kIters = kNVec / kStride;                // exactly 16
constexpr int kBatch = 4;
constexpr int kOuter = kIters / kBatch;                // 4

static_assert(kNVec % kStride == 0, "exact tiling");
static_assert(kStride % kDVec == 0, "column invariant across iterations");

__global__ __launch_bounds__(kBlock) void DiagonalLinear_kernel(
    const float* __restrict__ x,
    const float* __restrict__ w,
    const float* __restrict__ b,
    float* __restrict__ out) {
    const f32x4* __restrict__ x4 = reinterpret_cast<const f32x4*>(x);
    const f32x4* __restrict__ w4 = reinterpret_cast<const f32x4*>(w);
    const f32x4* __restrict__ b4 = reinterpret_cast<const f32x4*>(b);
    f32x4* __restrict__ o4 = reinterpret_cast<f32x4*>(out);

    const int start = blockIdx.x * blockDim.x + threadIdx.x;

    // stride % kDVec == 0 -> column index is invariant across the loop.
    const int c = start & (kDVec - 1);
    const f32x4 wv = w4[c];   // cached (16 KiB, L1/L2-resident)
    const f32x4 bv = b4[c];

    for (int k = 0; k < kOuter; ++k) {
        const int i0 = start + (k * kBatch + 0) * kStride;
        const int i1 = start + (k * kBatch + 1) * kStride;
        const int i2 = start + (k * kBatch + 2) * kStride;
        const int i3 = start + (k * kBatch + 3) * kStride;
        // 4 independent loads issue back-to-back (no aliasing w/ out per
        // __restrict__), then dependent FMA+stores drain them in order.
        f32x4 a0 = x4[i0];
        f32x4 a1 = x4[i1];
        f32x4 a2 = x4[i2];
        f32x4 a3 = x4[i3];
        f32x4 ov;
        ov.x = fmaf(a0.x, wv.x, bv.x); ov.y = fmaf(a0.y, wv.y, bv.y);
        ov.z = fmaf(a0.z, wv.z, bv.z); ov.w = fmaf(a0.w, wv.w, bv.w);
        o4[i0] = ov;
        ov.x = fmaf(a1.x, wv.x, bv.x); ov.y = fmaf(a1.y, wv.y, bv.y);
        ov.z = fmaf(a1.z, wv.z, bv.z); ov.w = fmaf(a1.w, wv.w, bv.w);
        o4[i1] = ov;
        ov.x = fmaf(a2.x, wv.x, bv.x); ov.y = fmaf(a2.y, wv.y, bv.y);
        ov.z = fmaf(a2.z, wv.z, bv.z); ov.w = fmaf(a2.w, wv.w, bv.w);
        o4[i2] = ov;
        ov.x = fmaf(a3.x, wv.x, bv.x); ov.y = fmaf(a3.y, wv.y, bv.y);
        ov.z = fmaf(a3.z, wv.z, bv.z); ov.w = fmaf(a3.w, wv.w, bv.w);
        o4[i3] = ov;
    }
}

extern "C" void kernel_launch(void* const* d_in, const int* in_sizes, int n_in,
                              void* d_out, int out_size, void* d_ws, size_t ws_size,
                              hipStream_t stream) {
    const float* x = (const float*)d_in[0];
    const float* w = (const float*)d_in[1];
    const float* b = (const float*)d_in[2];
    float* out = (float*)d_out;

    DiagonalLinear_kernel<<<kGrid, kBlock, 0, stream>>>(x, w, b, out);
}

// Round 6
// 42.137 us; speedup vs baseline: 1.1641x; 1.1641x over previous
//
#include <hip/hip_runtime.h>

// out[n, d] = x[n, d] * weight[d] + bias[d]
// x: (8192, 4096) fp32, weight/bias: (4096,) fp32, out: (8192, 4096) fp32.
// Memory-bound: 268.4 MB total traffic -> ~42.7 us @ 6.29 TB/s measured
// float4-copy ceiling (same 1:1 r:w mix).
// R1: 45.95 us plain grid-stride, cached path (93% of ceiling)  <- best
// R2/R3: nontemporal ld/st -> 50.96 us (nt bypass hurts; reverted)
// R4: #pragma unroll 4 -> 46.96 us (neutral/worse)
// R5: explicit 4-wide batch -> 49.05 us (occupancy fell to 45%; worse)
// Lesson: TLP saturates the bus; per-wave ILP tricks only perturb it.
// R6: flat one-float4-per-thread launch (copyBuffer-style, no loop at all).
//     If >= 45.5 us -> R1 is the practical roofline.

typedef float f32x4 __attribute__((ext_vector_type(4)));

constexpr int kD = 4096;
constexpr int kTokens = 8192;
constexpr long long kN = (long long)kTokens * kD;      // 33554432 elements
constexpr int kNVec = (int)(kN / 4);                   // 8388608 float4s
constexpr int kDVec = kD / 4;                          // 1024 float4s per row
constexpr int kBlock = 256;
constexpr int kGrid = kNVec / kBlock;                  // 32768 blocks, exact

static_assert(kNVec % kBlock == 0, "exact tiling");

__global__ __launch_bounds__(kBlock) void DiagonalLinear_kernel(
    const float* __restrict__ x,
    const float* __restrict__ w,
    const float* __restrict__ b,
    float* __restrict__ out) {
    const f32x4* __restrict__ x4 = reinterpret_cast<const f32x4*>(x);
    const f32x4* __restrict__ w4 = reinterpret_cast<const f32x4*>(w);
    const f32x4* __restrict__ b4 = reinterpret_cast<const f32x4*>(b);
    f32x4* __restrict__ o4 = reinterpret_cast<f32x4*>(out);

    const int i = blockIdx.x * kBlock + threadIdx.x;   // one float4 per thread
    const int c = i & (kDVec - 1);                     // column index

    const f32x4 wv = w4[c];   // 16 KiB, L1/L2-resident
    const f32x4 bv = b4[c];
    f32x4 xv = x4[i];
    f32x4 ov;
    ov.x = fmaf(xv.x, wv.x, bv.x);
    ov.y = fmaf(xv.y, wv.y, bv.y);
    ov.z = fmaf(xv.z, wv.z, bv.z);
    ov.w = fmaf(xv.w, wv.w, bv.w);
    o4[i] = ov;
}

extern "C" void kernel_launch(void* const* d_in, const int* in_sizes, int n_in,
                              void* d_out, int out_size, void* d_ws, size_t ws_size,
                              hipStream_t stream) {
    const float* x = (const float*)d_in[0];
    const float* w = (const float*)d_in[1];
    const float* b = (const float*)d_in[2];
    float* out = (float*)d_out;

    DiagonalLinear_kernel<<<kGrid, kBlock, 0, stream>>>(x, w, b, out);
}